// Round 2
// baseline (1856.529 us; speedup 1.0000x reference)
//
#include <hip/hip_runtime.h>
#include <hip/hip_bf16.h>
#include <cstdint>

#define NB 2
#define NPER 65536
#define NPTS (NB*NPER)
#define CDIM 128
#define SV 64
#define VOX (SV*SV*SV)
#define WCOLS 1217
#define WSTRIDE 1232   // padded row stride (multiple of 16 floats -> 64B-aligned rows)

// Padded Wh3 lives in a static device buffer (rewritten every call; deterministic).
__device__ __align__(16) float g_Wh3p[32*WSTRIDE];

__global__ __launch_bounds__(256) void pad_wh3_kernel(const float* __restrict__ Wh3){
    int idx = blockIdx.x*256 + threadIdx.x;
    if (idx < 32*WCOLS){
        int k = idx / WCOLS;
        int c = idx - k*WCOLS;
        g_Wh3p[k*WSTRIDE + c] = Wh3[idx];
    }
}

// c_plane [B][C=128][VOX] fp32 -> ct [B][VOX][C=128] bf16
__global__ __launch_bounds__(256) void transpose_kernel(const float* __restrict__ in,
                                                        __hip_bfloat162* __restrict__ out){
    __shared__ float tile[128][33];
    const int blk = blockIdx.x;        // NB * (VOX/32) blocks
    const int b  = blk >> 13;          // VOX/32 = 8192
    const int v0 = (blk & 8191) << 5;  // *32
    const int tx = threadIdx.x & 31;
    const int ty = threadIdx.x >> 5;   // 0..7
    const float* ip = in + (size_t)b*128*VOX + v0;
    #pragma unroll
    for (int cc = 0; cc < 16; cc++){
        int c = cc*8 + ty;
        tile[c][tx] = ip[(size_t)c*VOX + tx];
    }
    __syncthreads();
    const int c2 = threadIdx.x & 63;   // channel pair index 0..63
    const int vq = threadIdx.x >> 6;   // 0..3
    __hip_bfloat162* op = out + ((size_t)b*VOX + v0)*64;  // 64 bf16x2 per voxel
    #pragma unroll
    for (int vv = 0; vv < 8; vv++){
        int v = vv*4 + vq;
        __hip_bfloat162 pk;
        pk.x = __float2bfloat16(tile[2*c2    ][v]);
        pk.y = __float2bfloat16(tile[2*c2 + 1][v]);
        op[(size_t)v*64 + c2] = pk;
    }
}

// wave-per-point trilinear sample from channel-last bf16 ct; lane handles 2 channels
__global__ __launch_bounds__(256) void sample_kernel(const float* __restrict__ pcl_mem,
                                                     const __hip_bfloat162* __restrict__ ct,
                                                     float* __restrict__ feats){
    const int tid  = threadIdx.x;
    const int lane = tid & 63;
    const int p    = blockIdx.x*4 + (tid >> 6);
    const int b    = p >> 16;

    float v0 = pcl_mem[3*p+0], v1 = pcl_mem[3*p+1], v2 = pcl_mem[3*p+2];
    auto src = [](float v){
        float g = 2.0f*v/63.0f - 1.0f;
        g = fminf(fmaxf(g, -2.0f), 2.0f);
        float t = (g + 1.0f)*0.5f*63.0f;
        return fminf(fmaxf(t, 0.0f), 63.0f);
    };
    float ix = src(v0), iy = src(v1), iz = src(v2);
    float fx = floorf(ix), fy = floorf(iy), fz = floorf(iz);
    float wx = ix-fx, wy = iy-fy, wz = iz-fz;
    int x0 = min(max((int)fx,0),63); int x1 = min(x0+1,63);
    int y0 = min(max((int)fy,0),63); int y1 = min(y0+1,63);
    int z0 = min(max((int)fz,0),63); int z1 = min(z0+1,63);
    float wx0 = 1.f-wx, wy0 = 1.f-wy, wz0 = 1.f-wz;

    const __hip_bfloat162* base = ct + (size_t)b*VOX*64 + lane;
    float ax = 0.f, ay = 0.f;
#define CORNER(zz,yy,xx,wgt) { \
        __hip_bfloat162 cv = base[(size_t)(((zz)*64+(yy))*64+(xx))*64]; \
        float w_ = (wgt); \
        ax = fmaf(w_, __bfloat162float(cv.x), ax); \
        ay = fmaf(w_, __bfloat162float(cv.y), ay); }
    CORNER(z0,y0,x0, wz0*wy0*wx0);
    CORNER(z0,y0,x1, wz0*wy0*wx );
    CORNER(z0,y1,x0, wz0*wy *wx0);
    CORNER(z0,y1,x1, wz0*wy *wx );
    CORNER(z1,y0,x0, wz *wy0*wx0);
    CORNER(z1,y0,x1, wz *wy0*wx );
    CORNER(z1,y1,x0, wz *wy *wx0);
    CORNER(z1,y1,x1, wz *wy *wx );
#undef CORNER
    ((float2*)(feats + (size_t)p*CDIM))[lane] = make_float2(ax, ay);
}

// fallback (ws too small): thread per (point, channel), original layout, fp32
__global__ __launch_bounds__(256) void sample_slow_kernel(const float* __restrict__ pcl_mem,
                                                          const float* __restrict__ cpl,
                                                          float* __restrict__ feats){
    int gid = blockIdx.x*256 + threadIdx.x;   // p*128 + c
    int p = gid >> 7; int c = gid & 127;
    int b = p >> 16;
    float v0 = pcl_mem[3*p+0], v1 = pcl_mem[3*p+1], v2 = pcl_mem[3*p+2];
    auto src = [](float v){
        float g = 2.0f*v/63.0f - 1.0f;
        g = fminf(fmaxf(g, -2.0f), 2.0f);
        float t = (g + 1.0f)*0.5f*63.0f;
        return fminf(fmaxf(t, 0.0f), 63.0f);
    };
    float ix = src(v0), iy = src(v1), iz = src(v2);
    float fx = floorf(ix), fy = floorf(iy), fz = floorf(iz);
    float wx = ix-fx, wy = iy-fy, wz = iz-fz;
    int x0 = min(max((int)fx,0),63); int x1 = min(x0+1,63);
    int y0 = min(max((int)fy,0),63); int y1 = min(y0+1,63);
    int z0 = min(max((int)fz,0),63); int z1 = min(z0+1,63);
    float wx0 = 1.f-wx, wy0 = 1.f-wy, wz0 = 1.f-wz;
    const float* base = cpl + ((size_t)(b*128 + c))*VOX;
    float acc = 0.f;
    acc = fmaf(wz0*wy0*wx0, base[(z0*64+y0)*64+x0], acc);
    acc = fmaf(wz0*wy0*wx , base[(z0*64+y0)*64+x1], acc);
    acc = fmaf(wz0*wy *wx0, base[(z0*64+y1)*64+x0], acc);
    acc = fmaf(wz0*wy *wx , base[(z0*64+y1)*64+x1], acc);
    acc = fmaf(wz *wy0*wx0, base[(z1*64+y0)*64+x0], acc);
    acc = fmaf(wz *wy0*wx , base[(z1*64+y0)*64+x1], acc);
    acc = fmaf(wz *wy *wx0, base[(z1*64+y1)*64+x0], acc);
    acc = fmaf(wz *wy *wx , base[(z1*64+y1)*64+x1], acc);
    feats[gid] = acc;
}

__device__ __forceinline__ void fma4(float (&acc)[32], int jv, float s, float4 w){
    acc[4*jv+0] = fmaf(s, w.x, acc[4*jv+0]);
    acc[4*jv+1] = fmaf(s, w.y, acc[4*jv+1]);
    acc[4*jv+2] = fmaf(s, w.z, acc[4*jv+2]);
    acc[4*jv+3] = fmaf(s, w.w, acc[4*jv+3]);
}
__device__ __forceinline__ void fma4h(float (&acc)[16], int t, float s, float4 w){
    acc[4*t+0] = fmaf(s, w.x, acc[4*t+0]);
    acc[4*t+1] = fmaf(s, w.y, acc[4*t+1]);
    acc[4*t+2] = fmaf(s, w.z, acc[4*t+2]);
    acc[4*t+3] = fmaf(s, w.w, acc[4*t+3]);
}

// 2-waves-per-point-group fused MLP + hypernetwork.
// Block = 256 threads = 4 waves; waves (0,1) share points 0..63 of the block,
// waves (2,3) share points 64..127. jh = wave&1 selects the j-half (wave-uniform
// so all weight loads stay scalar). Phases h1/h2 duplicated across the pair.
__global__ __launch_bounds__(256, 4) void mlp_kernel(
        const float* __restrict__ pcl_mem,
        const float* __restrict__ Wh1, const float* __restrict__ bh1,
        const float* __restrict__ Wh2, const float* __restrict__ bh2,
        const float* __restrict__ bh3,
        const float* __restrict__ feats,
        float* __restrict__ outp)
{
    __shared__ float lds_a1[32][128];   // a1 per point-column (written by both halves)
    __shared__ float lds_f[128];        // o3 partial exchange

    const int tid  = threadIdx.x;
    const int w    = tid >> 6;
    const int lane = tid & 63;
    const int jh   = w & 1;                      // wave-uniform j-half
    const int pcol = ((w >> 1) << 6) + lane;     // 0..127 point within block
    const int p    = blockIdx.x*128 + pcol;

    float xv0, xv1, xv2;
    {
        float v0 = pcl_mem[3*p+0], v1 = pcl_mem[3*p+1], v2 = pcl_mem[3*p+2];
        xv0 = v0 - truncf(v0) - 0.5f;
        xv1 = v1 - truncf(v1) - 0.5f;
        xv2 = v2 - truncf(v2) - 0.5f;
    }

    const float4* f4  = (const float4*)(feats + (size_t)p*CDIM);
    const float4* W1q = (const float4*)Wh1;
    const float4* W2q = (const float4*)Wh2;
    const float4* W3q = (const float4*)g_Wh3p;
    const float4* b1q = (const float4*)bh1;
    const float4* b2q = (const float4*)bh2;
    const float4* b3q = (const float4*)bh3;
    const int RS = WSTRIDE/4;   // 308 float4 per Wh3p row

    // ---- h1 = leaky(feats @ Wh1 + bh1)  (full, duplicated across the pair) ----
    float h1[32];
    #pragma unroll
    for (int jv=0;jv<8;jv++){ float4 bv=b1q[jv]; h1[4*jv]=bv.x; h1[4*jv+1]=bv.y; h1[4*jv+2]=bv.z; h1[4*jv+3]=bv.w; }
    for (int c4=0;c4<32;c4++){
        float4 f = f4[c4];
        float fs[4] = {f.x, f.y, f.z, f.w};
        #pragma unroll
        for (int cc=0;cc<4;cc++){
            #pragma unroll
            for (int jv=0;jv<8;jv++)
                fma4(h1, jv, fs[cc], W1q[(c4*4+cc)*8 + jv]);
        }
    }
    #pragma unroll
    for (int j=0;j<32;j++){ h1[j] = fmaxf(h1[j], 0.01f*h1[j]); }   // h1a in place

    // ---- h2 = leaky(h1a @ Wh2 + bh2)  (full, duplicated) ----
    float h2[32];
    #pragma unroll
    for (int kv=0;kv<8;kv++){ float4 bv=b2q[kv]; h2[4*kv]=bv.x; h2[4*kv+1]=bv.y; h2[4*kv+2]=bv.z; h2[4*kv+3]=bv.w; }
    #pragma unroll
    for (int j=0;j<32;j++){
        float aj = h1[j];
        #pragma unroll
        for (int kv=0;kv<8;kv++) fma4(h2, kv, aj, W2q[j*8+kv]);
    }
    #pragma unroll
    for (int k=0;k<32;k++){ h2[k] = fmaxf(h2[k], 0.01f*h2[k]); }   // h2a in place

    // ---- phase C: o1 (this wave's j-half): hw cols 0..127 fused with x ----
    float o1h[16];
    #pragma unroll
    for (int t=0;t<4;t++){
        float4 ba=b3q[4*jh+t], bb=b3q[8+4*jh+t], bc=b3q[16+4*jh+t], bd=b3q[24+4*jh+t];
        o1h[4*t+0] = fmaf(xv0,ba.x, fmaf(xv1,bb.x, fmaf(xv2,bc.x, bd.x)));
        o1h[4*t+1] = fmaf(xv0,ba.y, fmaf(xv1,bb.y, fmaf(xv2,bc.y, bd.y)));
        o1h[4*t+2] = fmaf(xv0,ba.z, fmaf(xv1,bb.z, fmaf(xv2,bc.z, bd.z)));
        o1h[4*t+3] = fmaf(xv0,ba.w, fmaf(xv1,bb.w, fmaf(xv2,bc.w, bd.w)));
    }
    #pragma unroll
    for (int k=0;k<32;k++){
        float hk = h2[k];
        const float4* row = W3q + k*RS + 4*jh;
        #pragma unroll
        for (int t=0;t<4;t++){
            float4 wa=row[t], wb=row[8+t], wc=row[16+t], wd=row[24+t];
            float m0 = fmaf(xv0,wa.x, fmaf(xv1,wb.x, fmaf(xv2,wc.x, wd.x)));
            float m1 = fmaf(xv0,wa.y, fmaf(xv1,wb.y, fmaf(xv2,wc.y, wd.y)));
            float m2 = fmaf(xv0,wa.z, fmaf(xv1,wb.z, fmaf(xv2,wc.z, wd.z)));
            float m3 = fmaf(xv0,wa.w, fmaf(xv1,wb.w, fmaf(xv2,wc.w, wd.w)));
            o1h[4*t+0] = fmaf(hk, m0, o1h[4*t+0]);
            o1h[4*t+1] = fmaf(hk, m1, o1h[4*t+1]);
            o1h[4*t+2] = fmaf(hk, m2, o1h[4*t+2]);
            o1h[4*t+3] = fmaf(hk, m3, o1h[4*t+3]);
        }
    }
    #pragma unroll
    for (int t=0;t<16;t++){ float a=o1h[t]; lds_a1[jh*16+t][pcol] = fmaxf(a, 0.01f*a); }
    __syncthreads();

    // ---- phase D: o2 half init = hw cols 1152..1183 (this j-half) ----
    float o2h[16];
    #pragma unroll
    for (int t=0;t<4;t++){ float4 bv=b3q[288+4*jh+t]; o2h[4*t]=bv.x; o2h[4*t+1]=bv.y; o2h[4*t+2]=bv.z; o2h[4*t+3]=bv.w; }
    #pragma unroll
    for (int k=0;k<32;k++){
        const float4* row = W3q + k*RS + 288 + 4*jh;
        #pragma unroll
        for (int t=0;t<4;t++) fma4h(o2h, t, h2[k], row[t]);
    }

    // ---- phase E: o2h[j] += sum_i a1[i] * (bh3 + h2.Wh3)[128+i*32+j] ----
    for (int i=0;i<32;i++){
        float ai = lds_a1[i][pcol];
        float w2h[16];
        #pragma unroll
        for (int t=0;t<4;t++){ float4 bv=b3q[32+i*8+4*jh+t]; w2h[4*t]=bv.x; w2h[4*t+1]=bv.y; w2h[4*t+2]=bv.z; w2h[4*t+3]=bv.w; }
        #pragma unroll
        for (int k=0;k<32;k++){
            const float4* row = W3q + k*RS + 32 + i*8 + 4*jh;
            #pragma unroll
            for (int t=0;t<4;t++) fma4h(w2h, t, h2[k], row[t]);
        }
        #pragma unroll
        for (int t=0;t<16;t++) o2h[t] = fmaf(ai, w2h[t], o2h[t]);
    }

    // ---- final: o3 = leaky(o2) . W3' + b3' ----
    float w3h[16];
    #pragma unroll
    for (int t=0;t<4;t++){ float4 bv=b3q[296+4*jh+t]; w3h[4*t]=bv.x; w3h[4*t+1]=bv.y; w3h[4*t+2]=bv.z; w3h[4*t+3]=bv.w; }
    #pragma unroll
    for (int k=0;k<32;k++){
        const float4* row = W3q + k*RS + 296 + 4*jh;
        #pragma unroll
        for (int t=0;t<4;t++) fma4h(w3h, t, h2[k], row[t]);
    }
    float o3p = 0.f;
    if (jh == 0){   // wave-uniform branch
        o3p = bh3[1216];
        #pragma unroll
        for (int k=0;k<32;k++) o3p = fmaf(h2[k], g_Wh3p[k*WSTRIDE + 1216], o3p);
    }
    #pragma unroll
    for (int t=0;t<16;t++){ float a=o2h[t]; a = fmaxf(a, 0.01f*a); o3p = fmaf(a, w3h[t], o3p); }

    if (jh == 1) lds_f[pcol] = o3p;
    __syncthreads();
    if (jh == 0) outp[p] = o3p + lds_f[pcol];
}

extern "C" void kernel_launch(void* const* d_in, const int* in_sizes, int n_in,
                              void* d_out, int out_size, void* d_ws, size_t ws_size,
                              hipStream_t stream)
{
    const float* pcl_mem = (const float*)d_in[1];
    const float* c_plane = (const float*)d_in[2];
    const float* Wh1     = (const float*)d_in[3];
    const float* bh1     = (const float*)d_in[4];
    const float* Wh2     = (const float*)d_in[5];
    const float* bh2     = (const float*)d_in[6];
    const float* Wh3     = (const float*)d_in[7];
    const float* bh3     = (const float*)d_in[8];
    float* outp  = (float*)d_out;
    float* feats = outp + NPTS;

    pad_wh3_kernel<<<(32*WCOLS+255)/256, 256, 0, stream>>>(Wh3);

    const size_t ct_bytes = (size_t)NB*VOX*CDIM*sizeof(__hip_bfloat16);   // 128 MiB
    if (ws_size >= ct_bytes) {
        __hip_bfloat162* ct = (__hip_bfloat162*)d_ws;
        transpose_kernel<<<NB*(VOX/32), 256, 0, stream>>>(c_plane, ct);
        sample_kernel<<<NPTS/4, 256, 0, stream>>>(pcl_mem, ct, feats);
    } else {
        sample_slow_kernel<<<(NPTS*CDIM)/256, 256, 0, stream>>>(pcl_mem, c_plane, feats);
    }

    mlp_kernel<<<NPTS/128, 256, 0, stream>>>(pcl_mem, Wh1, bh1, Wh2, bh2, bh3, feats, outp);
}

// Round 3
// 1059.201 us; speedup vs baseline: 1.7528x; 1.7528x over previous
//
#include <hip/hip_runtime.h>
#include <hip/hip_bf16.h>
#include <cstdint>

#define NB 2
#define NPER 65536
#define NPTS (NB*NPER)
#define CDIM 128
#define SV 64
#define VOX (SV*SV*SV)
#define WCOLS 1217
#define WSTRIDE 1232   // padded row stride (multiple of 16 floats -> 64B-aligned rows)

// Padded Wh3 lives in a static device buffer (rewritten every call; deterministic).
__device__ __align__(16) float g_Wh3p[32*WSTRIDE];

__global__ __launch_bounds__(256) void pad_wh3_kernel(const float* __restrict__ Wh3){
    int idx = blockIdx.x*256 + threadIdx.x;
    if (idx < 32*WCOLS){
        int k = idx / WCOLS;
        int c = idx - k*WCOLS;
        g_Wh3p[k*WSTRIDE + c] = Wh3[idx];
    }
}

// c_plane [B][C=128][VOX] fp32 -> ct [B][VOX][C=128] bf16
__global__ __launch_bounds__(256) void transpose_kernel(const float* __restrict__ in,
                                                        __hip_bfloat162* __restrict__ out){
    __shared__ float tile[128][33];
    const int blk = blockIdx.x;        // NB * (VOX/32) blocks
    const int b  = blk >> 13;          // VOX/32 = 8192
    const int v0 = (blk & 8191) << 5;  // *32
    const int tx = threadIdx.x & 31;
    const int ty = threadIdx.x >> 5;   // 0..7
    const float* ip = in + (size_t)b*128*VOX + v0;
    #pragma unroll
    for (int cc = 0; cc < 16; cc++){
        int c = cc*8 + ty;
        tile[c][tx] = ip[(size_t)c*VOX + tx];
    }
    __syncthreads();
    const int c2 = threadIdx.x & 63;   // channel pair index 0..63
    const int vq = threadIdx.x >> 6;   // 0..3
    __hip_bfloat162* op = out + ((size_t)b*VOX + v0)*64;  // 64 bf16x2 per voxel
    #pragma unroll
    for (int vv = 0; vv < 8; vv++){
        int v = vv*4 + vq;
        __hip_bfloat162 pk;
        pk.x = __float2bfloat16(tile[2*c2    ][v]);
        pk.y = __float2bfloat16(tile[2*c2 + 1][v]);
        op[(size_t)v*64 + c2] = pk;
    }
}

// wave-per-point trilinear sample from channel-last bf16 ct; lane handles 2 channels
__global__ __launch_bounds__(256) void sample_kernel(const float* __restrict__ pcl_mem,
                                                     const __hip_bfloat162* __restrict__ ct,
                                                     float* __restrict__ feats){
    const int tid  = threadIdx.x;
    const int lane = tid & 63;
    const int p    = blockIdx.x*4 + (tid >> 6);
    const int b    = p >> 16;

    float v0 = pcl_mem[3*p+0], v1 = pcl_mem[3*p+1], v2 = pcl_mem[3*p+2];
    auto src = [](float v){
        float g = 2.0f*v/63.0f - 1.0f;
        g = fminf(fmaxf(g, -2.0f), 2.0f);
        float t = (g + 1.0f)*0.5f*63.0f;
        return fminf(fmaxf(t, 0.0f), 63.0f);
    };
    float ix = src(v0), iy = src(v1), iz = src(v2);
    float fx = floorf(ix), fy = floorf(iy), fz = floorf(iz);
    float wx = ix-fx, wy = iy-fy, wz = iz-fz;
    int x0 = min(max((int)fx,0),63); int x1 = min(x0+1,63);
    int y0 = min(max((int)fy,0),63); int y1 = min(y0+1,63);
    int z0 = min(max((int)fz,0),63); int z1 = min(z0+1,63);
    float wx0 = 1.f-wx, wy0 = 1.f-wy, wz0 = 1.f-wz;

    const __hip_bfloat162* base = ct + (size_t)b*VOX*64 + lane;
    float ax = 0.f, ay = 0.f;
#define CORNER(zz,yy,xx,wgt) { \
        __hip_bfloat162 cv = base[(size_t)(((zz)*64+(yy))*64+(xx))*64]; \
        float w_ = (wgt); \
        ax = fmaf(w_, __bfloat162float(cv.x), ax); \
        ay = fmaf(w_, __bfloat162float(cv.y), ay); }
    CORNER(z0,y0,x0, wz0*wy0*wx0);
    CORNER(z0,y0,x1, wz0*wy0*wx );
    CORNER(z0,y1,x0, wz0*wy *wx0);
    CORNER(z0,y1,x1, wz0*wy *wx );
    CORNER(z1,y0,x0, wz *wy0*wx0);
    CORNER(z1,y0,x1, wz *wy0*wx );
    CORNER(z1,y1,x0, wz *wy *wx0);
    CORNER(z1,y1,x1, wz *wy *wx );
#undef CORNER
    ((float2*)(feats + (size_t)p*CDIM))[lane] = make_float2(ax, ay);
}

// fallback (ws too small): thread per (point, channel), original layout, fp32
__global__ __launch_bounds__(256) void sample_slow_kernel(const float* __restrict__ pcl_mem,
                                                          const float* __restrict__ cpl,
                                                          float* __restrict__ feats){
    int gid = blockIdx.x*256 + threadIdx.x;   // p*128 + c
    int p = gid >> 7; int c = gid & 127;
    int b = p >> 16;
    float v0 = pcl_mem[3*p+0], v1 = pcl_mem[3*p+1], v2 = pcl_mem[3*p+2];
    auto src = [](float v){
        float g = 2.0f*v/63.0f - 1.0f;
        g = fminf(fmaxf(g, -2.0f), 2.0f);
        float t = (g + 1.0f)*0.5f*63.0f;
        return fminf(fmaxf(t, 0.0f), 63.0f);
    };
    float ix = src(v0), iy = src(v1), iz = src(v2);
    float fx = floorf(ix), fy = floorf(iy), fz = floorf(iz);
    float wx = ix-fx, wy = iy-fy, wz = iz-fz;
    int x0 = min(max((int)fx,0),63); int x1 = min(x0+1,63);
    int y0 = min(max((int)fy,0),63); int y1 = min(y0+1,63);
    int z0 = min(max((int)fz,0),63); int z1 = min(z0+1,63);
    float wx0 = 1.f-wx, wy0 = 1.f-wy, wz0 = 1.f-wz;
    const float* base = cpl + ((size_t)(b*128 + c))*VOX;
    float acc = 0.f;
    acc = fmaf(wz0*wy0*wx0, base[(z0*64+y0)*64+x0], acc);
    acc = fmaf(wz0*wy0*wx , base[(z0*64+y0)*64+x1], acc);
    acc = fmaf(wz0*wy *wx0, base[(z0*64+y1)*64+x0], acc);
    acc = fmaf(wz0*wy *wx , base[(z0*64+y1)*64+x1], acc);
    acc = fmaf(wz *wy0*wx0, base[(z1*64+y0)*64+x0], acc);
    acc = fmaf(wz *wy0*wx , base[(z1*64+y0)*64+x1], acc);
    acc = fmaf(wz *wy *wx0, base[(z1*64+y1)*64+x0], acc);
    acc = fmaf(wz *wy *wx , base[(z1*64+y1)*64+x1], acc);
    feats[gid] = acc;
}

__device__ __forceinline__ void fma4h(float (&acc)[16], int t, float s, float4 w){
    acc[4*t+0] = fmaf(s, w.x, acc[4*t+0]);
    acc[4*t+1] = fmaf(s, w.y, acc[4*t+1]);
    acc[4*t+2] = fmaf(s, w.z, acc[4*t+2]);
    acc[4*t+3] = fmaf(s, w.w, acc[4*t+3]);
}

// 2-waves-per-point fused MLP + hypernetwork.
// Block = 256 threads = 4 waves; waves (0,1) share points 0..63 of the block,
// waves (2,3) share points 64..127. jh (readfirstlane -> SGPR, wave-uniform so
// all weight indices stay scalar) selects the j/k-half each wave owns.
__global__ __launch_bounds__(256) void mlp_kernel(
        const float* __restrict__ pcl_mem,
        const float* __restrict__ Wh1, const float* __restrict__ bh1,
        const float* __restrict__ Wh2, const float* __restrict__ bh2,
        const float* __restrict__ bh3,
        const float* __restrict__ feats,
        float* __restrict__ outp)
{
    __shared__ float lds_buf1[32][128];  // h1, later a1 (reused)
    __shared__ float lds_h2[32][128];    // h2 exchange
    __shared__ float lds_f[128];         // o3 partial exchange

    const int tid  = threadIdx.x;
    const int w    = tid >> 6;
    const int lane = tid & 63;
    const int jh   = __builtin_amdgcn_readfirstlane(w & 1);  // wave-uniform half
    const int pcol = ((w >> 1) << 6) + lane;                 // 0..127 point within block
    const int p    = blockIdx.x*128 + pcol;

    float xv0, xv1, xv2;
    {
        float v0 = pcl_mem[3*p+0], v1 = pcl_mem[3*p+1], v2 = pcl_mem[3*p+2];
        xv0 = v0 - truncf(v0) - 0.5f;
        xv1 = v1 - truncf(v1) - 0.5f;
        xv2 = v2 - truncf(v2) - 0.5f;
    }

    const float4* f4  = (const float4*)(feats + (size_t)p*CDIM);
    const float4* W1q = (const float4*)Wh1;
    const float4* W2q = (const float4*)Wh2;
    const float4* W3q = (const float4*)g_Wh3p;
    const float4* b1q = (const float4*)bh1;
    const float4* b2q = (const float4*)bh2;
    const float4* b3q = (const float4*)bh3;
    const int RS = WSTRIDE/4;   // 308 float4 per Wh3p row

    // ---- phase A: h1 half (this wave's 16 j's) ----
    float h1h[16];
    #pragma unroll
    for (int t=0;t<4;t++){ float4 bv=b1q[4*jh+t]; h1h[4*t]=bv.x; h1h[4*t+1]=bv.y; h1h[4*t+2]=bv.z; h1h[4*t+3]=bv.w; }
    for (int c4=0;c4<32;c4++){
        float4 f = f4[c4];
        float fs[4] = {f.x, f.y, f.z, f.w};
        #pragma unroll
        for (int cc=0;cc<4;cc++){
            #pragma unroll
            for (int t=0;t<4;t++)
                fma4h(h1h, t, fs[cc], W1q[(c4*4+cc)*8 + 4*jh + t]);
        }
    }
    #pragma unroll
    for (int t=0;t<16;t++){ float a=h1h[t]; lds_buf1[jh*16+t][pcol] = fmaxf(a, 0.01f*a); }
    __syncthreads();

    // ---- phase B: h2 half from full h1 (via LDS) ----
    float h2h[16];
    #pragma unroll
    for (int t=0;t<4;t++){ float4 bv=b2q[4*jh+t]; h2h[4*t]=bv.x; h2h[4*t+1]=bv.y; h2h[4*t+2]=bv.z; h2h[4*t+3]=bv.w; }
    #pragma unroll
    for (int j=0;j<32;j++){
        float aj = lds_buf1[j][pcol];
        #pragma unroll
        for (int t=0;t<4;t++) fma4h(h2h, t, aj, W2q[j*8 + 4*jh + t]);
    }
    #pragma unroll
    for (int t=0;t<16;t++){ float a=h2h[t]; lds_h2[jh*16+t][pcol] = fmaxf(a, 0.01f*a); }
    __syncthreads();
    float h2[32];
    #pragma unroll
    for (int k=0;k<32;k++) h2[k] = lds_h2[k][pcol];

    // ---- phase C: o1 (this wave's j-half): hw cols 0..127 fused with x ----
    float o1h[16];
    #pragma unroll
    for (int t=0;t<4;t++){
        float4 ba=b3q[4*jh+t], bb=b3q[8+4*jh+t], bc=b3q[16+4*jh+t], bd=b3q[24+4*jh+t];
        o1h[4*t+0] = fmaf(xv0,ba.x, fmaf(xv1,bb.x, fmaf(xv2,bc.x, bd.x)));
        o1h[4*t+1] = fmaf(xv0,ba.y, fmaf(xv1,bb.y, fmaf(xv2,bc.y, bd.y)));
        o1h[4*t+2] = fmaf(xv0,ba.z, fmaf(xv1,bb.z, fmaf(xv2,bc.z, bd.z)));
        o1h[4*t+3] = fmaf(xv0,ba.w, fmaf(xv1,bb.w, fmaf(xv2,bc.w, bd.w)));
    }
    #pragma unroll
    for (int k=0;k<32;k++){
        float hk = h2[k];
        const float4* row = W3q + k*RS + 4*jh;
        #pragma unroll
        for (int t=0;t<4;t++){
            float4 wa=row[t], wb=row[8+t], wc=row[16+t], wd=row[24+t];
            float m0 = fmaf(xv0,wa.x, fmaf(xv1,wb.x, fmaf(xv2,wc.x, wd.x)));
            float m1 = fmaf(xv0,wa.y, fmaf(xv1,wb.y, fmaf(xv2,wc.y, wd.y)));
            float m2 = fmaf(xv0,wa.z, fmaf(xv1,wb.z, fmaf(xv2,wc.z, wd.z)));
            float m3 = fmaf(xv0,wa.w, fmaf(xv1,wb.w, fmaf(xv2,wc.w, wd.w)));
            o1h[4*t+0] = fmaf(hk, m0, o1h[4*t+0]);
            o1h[4*t+1] = fmaf(hk, m1, o1h[4*t+1]);
            o1h[4*t+2] = fmaf(hk, m2, o1h[4*t+2]);
            o1h[4*t+3] = fmaf(hk, m3, o1h[4*t+3]);
        }
    }
    #pragma unroll
    for (int t=0;t<16;t++){ float a=o1h[t]; lds_buf1[jh*16+t][pcol] = fmaxf(a, 0.01f*a); }  // a1
    __syncthreads();

    // ---- phase D: o2 half init = hw cols 1152..1183 (this j-half) ----
    float o2h[16];
    #pragma unroll
    for (int t=0;t<4;t++){ float4 bv=b3q[288+4*jh+t]; o2h[4*t]=bv.x; o2h[4*t+1]=bv.y; o2h[4*t+2]=bv.z; o2h[4*t+3]=bv.w; }
    #pragma unroll
    for (int k=0;k<32;k++){
        const float4* row = W3q + k*RS + 288 + 4*jh;
        #pragma unroll
        for (int t=0;t<4;t++) fma4h(o2h, t, h2[k], row[t]);
    }

    // ---- phase E: o2h[j] += sum_i a1[i] * (bh3 + h2.Wh3)[128+i*32+j] ----
    for (int i=0;i<32;i++){
        float ai = lds_buf1[i][pcol];
        float w2h[16];
        #pragma unroll
        for (int t=0;t<4;t++){ float4 bv=b3q[32+i*8+4*jh+t]; w2h[4*t]=bv.x; w2h[4*t+1]=bv.y; w2h[4*t+2]=bv.z; w2h[4*t+3]=bv.w; }
        #pragma unroll
        for (int k=0;k<32;k++){
            const float4* row = W3q + k*RS + 32 + i*8 + 4*jh;
            #pragma unroll
            for (int t=0;t<4;t++) fma4h(w2h, t, h2[k], row[t]);
        }
        #pragma unroll
        for (int t=0;t<16;t++) o2h[t] = fmaf(ai, w2h[t], o2h[t]);
    }

    // ---- final: o3 = leaky(o2) . W3' + b3' ----
    float w3h[16];
    #pragma unroll
    for (int t=0;t<4;t++){ float4 bv=b3q[296+4*jh+t]; w3h[4*t]=bv.x; w3h[4*t+1]=bv.y; w3h[4*t+2]=bv.z; w3h[4*t+3]=bv.w; }
    #pragma unroll
    for (int k=0;k<32;k++){
        const float4* row = W3q + k*RS + 296 + 4*jh;
        #pragma unroll
        for (int t=0;t<4;t++) fma4h(w3h, t, h2[k], row[t]);
    }
    float o3p = 0.f;
    if (jh == 0){   // wave-uniform branch
        o3p = bh3[1216];
        #pragma unroll
        for (int k=0;k<32;k++) o3p = fmaf(h2[k], g_Wh3p[k*WSTRIDE + 1216], o3p);
    }
    #pragma unroll
    for (int t=0;t<16;t++){ float a=o2h[t]; a = fmaxf(a, 0.01f*a); o3p = fmaf(a, w3h[t], o3p); }

    if (jh == 1) lds_f[pcol] = o3p;
    __syncthreads();
    if (jh == 0) outp[p] = o3p + lds_f[pcol];
}

extern "C" void kernel_launch(void* const* d_in, const int* in_sizes, int n_in,
                              void* d_out, int out_size, void* d_ws, size_t ws_size,
                              hipStream_t stream)
{
    const float* pcl_mem = (const float*)d_in[1];
    const float* c_plane = (const float*)d_in[2];
    const float* Wh1     = (const float*)d_in[3];
    const float* bh1     = (const float*)d_in[4];
    const float* Wh2     = (const float*)d_in[5];
    const float* bh2     = (const float*)d_in[6];
    const float* Wh3     = (const float*)d_in[7];
    const float* bh3     = (const float*)d_in[8];
    float* outp  = (float*)d_out;
    float* feats = outp + NPTS;

    pad_wh3_kernel<<<(32*WCOLS+255)/256, 256, 0, stream>>>(Wh3);

    const size_t ct_bytes = (size_t)NB*VOX*CDIM*sizeof(__hip_bfloat16);   // 128 MiB
    if (ws_size >= ct_bytes) {
        __hip_bfloat162* ct = (__hip_bfloat162*)d_ws;
        transpose_kernel<<<NB*(VOX/32), 256, 0, stream>>>(c_plane, ct);
        sample_kernel<<<NPTS/4, 256, 0, stream>>>(pcl_mem, ct, feats);
    } else {
        sample_slow_kernel<<<(NPTS*CDIM)/256, 256, 0, stream>>>(pcl_mem, c_plane, feats);
    }

    mlp_kernel<<<NPTS/128, 256, 0, stream>>>(pcl_mem, Wh1, bh1, Wh2, bh2, bh3, feats, outp);
}

// Round 4
// 903.592 us; speedup vs baseline: 2.0546x; 1.1722x over previous
//
#include <hip/hip_runtime.h>
#include <hip/hip_bf16.h>
#include <cstdint>

#define NB 2
#define NPER 65536
#define NPTS (NB*NPER)
#define CDIM 128
#define SV 64
#define VOX (SV*SV*SV)
#define WCOLS 1217
#define WSTRIDE 1232   // padded row stride (multiple of 16 floats -> 64B-aligned rows)
#define RS (WSTRIDE/4) // 308 float4 per padded Wh3 row

// Padded Wh3 lives in a static device buffer (rewritten every call; deterministic).
__device__ __align__(16) float g_Wh3p[32*WSTRIDE];

__global__ __launch_bounds__(256) void pad_wh3_kernel(const float* __restrict__ Wh3){
    int idx = blockIdx.x*256 + threadIdx.x;
    if (idx < 32*WCOLS){
        int k = idx / WCOLS;
        int c = idx - k*WCOLS;
        g_Wh3p[k*WSTRIDE + c] = Wh3[idx];
    }
}

// c_plane [B][C=128][VOX] fp32 -> ct [B][VOX][C=128] bf16
__global__ __launch_bounds__(256) void transpose_kernel(const float* __restrict__ in,
                                                        __hip_bfloat162* __restrict__ out){
    __shared__ float tile[128][33];
    const int blk = blockIdx.x;        // NB * (VOX/32) blocks
    const int b  = blk >> 13;          // VOX/32 = 8192
    const int v0 = (blk & 8191) << 5;  // *32
    const int tx = threadIdx.x & 31;
    const int ty = threadIdx.x >> 5;   // 0..7
    const float* ip = in + (size_t)b*128*VOX + v0;
    #pragma unroll
    for (int cc = 0; cc < 16; cc++){
        int c = cc*8 + ty;
        tile[c][tx] = ip[(size_t)c*VOX + tx];
    }
    __syncthreads();
    const int c2 = threadIdx.x & 63;   // channel pair index 0..63
    const int vq = threadIdx.x >> 6;   // 0..3
    __hip_bfloat162* op = out + ((size_t)b*VOX + v0)*64;  // 64 bf16x2 per voxel
    #pragma unroll
    for (int vv = 0; vv < 8; vv++){
        int v = vv*4 + vq;
        __hip_bfloat162 pk;
        pk.x = __float2bfloat16(tile[2*c2    ][v]);
        pk.y = __float2bfloat16(tile[2*c2 + 1][v]);
        op[(size_t)v*64 + c2] = pk;
    }
}

// wave-per-point trilinear sample from channel-last bf16 ct; lane handles 2 channels
__global__ __launch_bounds__(256) void sample_kernel(const float* __restrict__ pcl_mem,
                                                     const __hip_bfloat162* __restrict__ ct,
                                                     float* __restrict__ feats){
    const int tid  = threadIdx.x;
    const int lane = tid & 63;
    const int p    = blockIdx.x*4 + (tid >> 6);
    const int b    = p >> 16;

    float v0 = pcl_mem[3*p+0], v1 = pcl_mem[3*p+1], v2 = pcl_mem[3*p+2];
    auto src = [](float v){
        float g = 2.0f*v/63.0f - 1.0f;
        g = fminf(fmaxf(g, -2.0f), 2.0f);
        float t = (g + 1.0f)*0.5f*63.0f;
        return fminf(fmaxf(t, 0.0f), 63.0f);
    };
    float ix = src(v0), iy = src(v1), iz = src(v2);
    float fx = floorf(ix), fy = floorf(iy), fz = floorf(iz);
    float wx = ix-fx, wy = iy-fy, wz = iz-fz;
    int x0 = min(max((int)fx,0),63); int x1 = min(x0+1,63);
    int y0 = min(max((int)fy,0),63); int y1 = min(y0+1,63);
    int z0 = min(max((int)fz,0),63); int z1 = min(z0+1,63);
    float wx0 = 1.f-wx, wy0 = 1.f-wy, wz0 = 1.f-wz;

    const __hip_bfloat162* base = ct + (size_t)b*VOX*64 + lane;
    float ax = 0.f, ay = 0.f;
#define CORNER(zz,yy,xx,wgt) { \
        __hip_bfloat162 cv = base[(size_t)(((zz)*64+(yy))*64+(xx))*64]; \
        float w_ = (wgt); \
        ax = fmaf(w_, __bfloat162float(cv.x), ax); \
        ay = fmaf(w_, __bfloat162float(cv.y), ay); }
    CORNER(z0,y0,x0, wz0*wy0*wx0);
    CORNER(z0,y0,x1, wz0*wy0*wx );
    CORNER(z0,y1,x0, wz0*wy *wx0);
    CORNER(z0,y1,x1, wz0*wy *wx );
    CORNER(z1,y0,x0, wz *wy0*wx0);
    CORNER(z1,y0,x1, wz *wy0*wx );
    CORNER(z1,y1,x0, wz *wy *wx0);
    CORNER(z1,y1,x1, wz *wy *wx );
#undef CORNER
    ((float2*)(feats + (size_t)p*CDIM))[lane] = make_float2(ax, ay);
}

// fallback (ws too small): thread per (point, channel), original layout, fp32
__global__ __launch_bounds__(256) void sample_slow_kernel(const float* __restrict__ pcl_mem,
                                                          const float* __restrict__ cpl,
                                                          float* __restrict__ feats){
    int gid = blockIdx.x*256 + threadIdx.x;   // p*128 + c
    int p = gid >> 7; int c = gid & 127;
    int b = p >> 16;
    float v0 = pcl_mem[3*p+0], v1 = pcl_mem[3*p+1], v2 = pcl_mem[3*p+2];
    auto src = [](float v){
        float g = 2.0f*v/63.0f - 1.0f;
        g = fminf(fmaxf(g, -2.0f), 2.0f);
        float t = (g + 1.0f)*0.5f*63.0f;
        return fminf(fmaxf(t, 0.0f), 63.0f);
    };
    float ix = src(v0), iy = src(v1), iz = src(v2);
    float fx = floorf(ix), fy = floorf(iy), fz = floorf(iz);
    float wx = ix-fx, wy = iy-fy, wz = iz-fz;
    int x0 = min(max((int)fx,0),63); int x1 = min(x0+1,63);
    int y0 = min(max((int)fy,0),63); int y1 = min(y0+1,63);
    int z0 = min(max((int)fz,0),63); int z1 = min(z0+1,63);
    float wx0 = 1.f-wx, wy0 = 1.f-wy, wz0 = 1.f-wz;
    const float* base = cpl + ((size_t)(b*128 + c))*VOX;
    float acc = 0.f;
    acc = fmaf(wz0*wy0*wx0, base[(z0*64+y0)*64+x0], acc);
    acc = fmaf(wz0*wy0*wx , base[(z0*64+y0)*64+x1], acc);
    acc = fmaf(wz0*wy *wx0, base[(z0*64+y1)*64+x0], acc);
    acc = fmaf(wz0*wy *wx , base[(z0*64+y1)*64+x1], acc);
    acc = fmaf(wz *wy0*wx0, base[(z1*64+y0)*64+x0], acc);
    acc = fmaf(wz *wy0*wx , base[(z1*64+y0)*64+x1], acc);
    acc = fmaf(wz *wy *wx0, base[(z1*64+y1)*64+x0], acc);
    acc = fmaf(wz *wy *wx , base[(z1*64+y1)*64+x1], acc);
    feats[gid] = acc;
}

__device__ __forceinline__ void fma8(float (&acc)[32], int jv, float s, float4 w){
    acc[4*jv+0] = fmaf(s, w.x, acc[4*jv+0]);
    acc[4*jv+1] = fmaf(s, w.y, acc[4*jv+1]);
    acc[4*jv+2] = fmaf(s, w.z, acc[4*jv+2]);
    acc[4*jv+3] = fmaf(s, w.w, acc[4*jv+3]);
}
__device__ __forceinline__ void fma4h(float (&acc)[16], int t, float s, float4 w){
    acc[4*t+0] = fmaf(s, w.x, acc[4*t+0]);
    acc[4*t+1] = fmaf(s, w.y, acc[4*t+1]);
    acc[4*t+2] = fmaf(s, w.z, acc[4*t+2]);
    acc[4*t+3] = fmaf(s, w.w, acc[4*t+3]);
}

// Barrier-free 2-waves-per-point fused MLP + hypernetwork.
// Block = 128 threads = 2 waves covering the SAME 64 points; jh = wave id
// (readfirstlane -> SGPR) selects the j-half for the heavy phase E. Phases
// A/B/C are duplicated across the pair (identical values), so LDS writes of
// h1a/h2a/a1 are benign duplicate writes: each wave reads after its own
// write -> no barrier anywhere except the single final o3 exchange.
__global__ __launch_bounds__(128) void mlp_kernel(
        const float* __restrict__ pcl_mem,
        const float* __restrict__ Wh1, const float* __restrict__ bh1,
        const float* __restrict__ Wh2, const float* __restrict__ bh2,
        const float* __restrict__ bh3,
        const float* __restrict__ feats,
        float* __restrict__ outp)
{
    __shared__ float lds_a[32*64];   // h1a, later a1 (per point-column)
    __shared__ float lds_h[32*64];   // h2a
    __shared__ float lds_f[64];      // o3 partial exchange

    const int tid  = threadIdx.x;
    const int lane = tid & 63;
    const int jh   = __builtin_amdgcn_readfirstlane(tid >> 6);  // 0 or 1, wave-uniform
    const int p    = blockIdx.x*64 + lane;

    float xv0, xv1, xv2;
    {
        float v0 = pcl_mem[3*p+0], v1 = pcl_mem[3*p+1], v2 = pcl_mem[3*p+2];
        xv0 = v0 - truncf(v0) - 0.5f;
        xv1 = v1 - truncf(v1) - 0.5f;
        xv2 = v2 - truncf(v2) - 0.5f;
    }

    const float4* f4  = (const float4*)(feats + (size_t)p*CDIM);
    const float4* W1q = (const float4*)Wh1;
    const float4* W2q = (const float4*)Wh2;
    const float4* W3q = (const float4*)g_Wh3p;
    const float4* b1q = (const float4*)bh1;
    const float4* b2q = (const float4*)bh2;
    const float4* b3q = (const float4*)bh3;

    // ---- phase A: h1 full (duplicated) ----
    {
        float h1[32];
        #pragma unroll
        for (int jv=0;jv<8;jv++){ float4 bv=b1q[jv]; h1[4*jv]=bv.x; h1[4*jv+1]=bv.y; h1[4*jv+2]=bv.z; h1[4*jv+3]=bv.w; }
        #pragma unroll 1
        for (int c4=0;c4<32;c4++){
            float4 f = f4[c4];
            float fs[4] = {f.x, f.y, f.z, f.w};
            #pragma unroll
            for (int cc=0;cc<4;cc++){
                #pragma unroll
                for (int jv=0;jv<8;jv++)
                    fma8(h1, jv, fs[cc], W1q[(c4*4+cc)*8 + jv]);
            }
        }
        #pragma unroll
        for (int j=0;j<32;j++){ float a=h1[j]; lds_a[j*64+lane] = fmaxf(a, 0.01f*a); }
    }

    // ---- phase B: h2 full (duplicated), h1a from LDS ----
    {
        float h2[32];
        #pragma unroll
        for (int kv=0;kv<8;kv++){ float4 bv=b2q[kv]; h2[4*kv]=bv.x; h2[4*kv+1]=bv.y; h2[4*kv+2]=bv.z; h2[4*kv+3]=bv.w; }
        #pragma unroll 1
        for (int j=0;j<32;j++){
            float aj = lds_a[j*64+lane];
            #pragma unroll
            for (int kv=0;kv<8;kv++) fma8(h2, kv, aj, W2q[j*8+kv]);
        }
        #pragma unroll
        for (int k=0;k<32;k++){ float a=h2[k]; lds_h[k*64+lane] = fmaxf(a, 0.01f*a); }
    }

    // ---- phase C: o1 full (duplicated): hw cols 0..127 fused with x ----
    {
        float o1[32];
        #pragma unroll
        for (int t=0;t<8;t++){
            float4 ba=b3q[t], bb=b3q[8+t], bc=b3q[16+t], bd=b3q[24+t];
            o1[4*t+0] = fmaf(xv0,ba.x, fmaf(xv1,bb.x, fmaf(xv2,bc.x, bd.x)));
            o1[4*t+1] = fmaf(xv0,ba.y, fmaf(xv1,bb.y, fmaf(xv2,bc.y, bd.y)));
            o1[4*t+2] = fmaf(xv0,ba.z, fmaf(xv1,bb.z, fmaf(xv2,bc.z, bd.z)));
            o1[4*t+3] = fmaf(xv0,ba.w, fmaf(xv1,bb.w, fmaf(xv2,bc.w, bd.w)));
        }
        #pragma unroll 1
        for (int k=0;k<32;k++){
            float hk = lds_h[k*64+lane];
            const float4* row = W3q + k*RS;
            #pragma unroll
            for (int t=0;t<8;t++){
                float4 wa=row[t], wb=row[8+t], wc=row[16+t], wd=row[24+t];
                float m0 = fmaf(xv0,wa.x, fmaf(xv1,wb.x, fmaf(xv2,wc.x, wd.x)));
                float m1 = fmaf(xv0,wa.y, fmaf(xv1,wb.y, fmaf(xv2,wc.y, wd.y)));
                float m2 = fmaf(xv0,wa.z, fmaf(xv1,wb.z, fmaf(xv2,wc.z, wd.z)));
                float m3 = fmaf(xv0,wa.w, fmaf(xv1,wb.w, fmaf(xv2,wc.w, wd.w)));
                o1[4*t+0] = fmaf(hk, m0, o1[4*t+0]);
                o1[4*t+1] = fmaf(hk, m1, o1[4*t+1]);
                o1[4*t+2] = fmaf(hk, m2, o1[4*t+2]);
                o1[4*t+3] = fmaf(hk, m3, o1[4*t+3]);
            }
        }
        #pragma unroll
        for (int j=0;j<32;j++){ float a=o1[j]; lds_a[j*64+lane] = fmaxf(a, 0.01f*a); }  // a1
    }

    // ---- phase D + final-weights: hw cols 1152..1216 (this j-half), rolled k ----
    float o2h[16], w3h[16];
    #pragma unroll
    for (int t=0;t<4;t++){ float4 bv=b3q[288+4*jh+t]; o2h[4*t]=bv.x; o2h[4*t+1]=bv.y; o2h[4*t+2]=bv.z; o2h[4*t+3]=bv.w; }
    #pragma unroll
    for (int t=0;t<4;t++){ float4 bv=b3q[296+4*jh+t]; w3h[4*t]=bv.x; w3h[4*t+1]=bv.y; w3h[4*t+2]=bv.z; w3h[4*t+3]=bv.w; }
    float o3p = (jh == 0) ? bh3[1216] : 0.0f;
    #pragma unroll 1
    for (int k=0;k<32;k++){
        float hk = lds_h[k*64+lane];
        const float4* rowD = W3q + k*RS + 288 + 4*jh;
        #pragma unroll
        for (int t=0;t<4;t++) fma4h(o2h, t, hk, rowD[t]);
        const float4* rowW = W3q + k*RS + 296 + 4*jh;
        #pragma unroll
        for (int t=0;t<4;t++) fma4h(w3h, t, hk, rowW[t]);
        if (jh == 0) o3p = fmaf(hk, g_Wh3p[k*WSTRIDE + 1216], o3p);
    }

    // ---- phase E (heavy): o2h[j] += sum_i a1[i]*(bh3 + h2.Wh3)[128+i*32+j-half] ----
    #pragma unroll 1
    for (int i=0;i<32;i++){
        float ai = lds_a[i*64+lane];
        float w2h[16];
        #pragma unroll
        for (int t=0;t<4;t++){ float4 bv=b3q[32+i*8+4*jh+t]; w2h[4*t]=bv.x; w2h[4*t+1]=bv.y; w2h[4*t+2]=bv.z; w2h[4*t+3]=bv.w; }
        #pragma unroll
        for (int k=0;k<32;k++){
            float hk = lds_h[k*64+lane];
            const float4* row = W3q + k*RS + 32 + i*8 + 4*jh;
            #pragma unroll
            for (int t=0;t<4;t++) fma4h(w2h, t, hk, row[t]);
        }
        #pragma unroll
        for (int t=0;t<16;t++) o2h[t] = fmaf(ai, w2h[t], o2h[t]);
    }

    // ---- final combine ----
    #pragma unroll
    for (int t=0;t<16;t++){ float a=o2h[t]; a = fmaxf(a, 0.01f*a); o3p = fmaf(a, w3h[t], o3p); }

    if (jh == 1) lds_f[lane] = o3p;
    __syncthreads();
    if (jh == 0) outp[p] = o3p + lds_f[lane];
}

extern "C" void kernel_launch(void* const* d_in, const int* in_sizes, int n_in,
                              void* d_out, int out_size, void* d_ws, size_t ws_size,
                              hipStream_t stream)
{
    const float* pcl_mem = (const float*)d_in[1];
    const float* c_plane = (const float*)d_in[2];
    const float* Wh1     = (const float*)d_in[3];
    const float* bh1     = (const float*)d_in[4];
    const float* Wh2     = (const float*)d_in[5];
    const float* bh2     = (const float*)d_in[6];
    const float* Wh3     = (const float*)d_in[7];
    const float* bh3     = (const float*)d_in[8];
    float* outp  = (float*)d_out;
    float* feats = outp + NPTS;

    pad_wh3_kernel<<<(32*WCOLS+255)/256, 256, 0, stream>>>(Wh3);

    const size_t ct_bytes = (size_t)NB*VOX*CDIM*sizeof(__hip_bfloat16);   // 128 MiB
    if (ws_size >= ct_bytes) {
        __hip_bfloat162* ct = (__hip_bfloat162*)d_ws;
        transpose_kernel<<<NB*(VOX/32), 256, 0, stream>>>(c_plane, ct);
        sample_kernel<<<NPTS/4, 256, 0, stream>>>(pcl_mem, ct, feats);
    } else {
        sample_slow_kernel<<<(NPTS*CDIM)/256, 256, 0, stream>>>(pcl_mem, c_plane, feats);
    }

    mlp_kernel<<<NPTS/64, 128, 0, stream>>>(pcl_mem, Wh1, bh1, Wh2, bh2, bh3, feats, outp);
}